// Round 1
// 90.387 us; speedup vs baseline: 1.0414x; 1.0414x over previous
//
#include <hip/hip_runtime.h>
#include <hip/hip_bf16.h>
#include <math.h>

// Problem dims (fixed by setup_inputs): B=64 samples, N=512 spins/flips, H=2048 hidden
constexpr int NB = 64;
constexpr int NN = 512;
constexpr int NH = 2048;
constexpr float LN2 = 0.6931471805599453f;

// Workspace layout (floats): only Tt[h][b] = tanh(theta) survives
constexpr size_t OFF_TT = 0;   // 2048*64

// ===== D1: GEMM + tanh -> Tt. 128 blocks x 512 thr (verified tiling from prior session).
__global__ __launch_bounds__(512) void k_theta(const float* __restrict__ W,
                                               const float* __restrict__ x,
                                               const float* __restrict__ bvec,
                                               float* __restrict__ Tt,
                                               float* __restrict__ out) {
    __shared__ float sm[10240];            // 40 KB
    int tid = threadIdx.x;
    int gb = blockIdx.x;                   // 0..127
    int ht = gb & 31;                      // 32 h-tiles of 64
    int bt = gb >> 5;                      // 4 b-tiles of 16
    // transpose x slice into LDS: xs[n][j], row stride 20 floats (80B, 16B-aligned)
    {
        int j = tid >> 5, c = tid & 31;                    // 16 rows x 32 cols
        const float4* xr = (const float4*)(x + (size_t)(bt * 16 + j) * NN);
#pragma unroll
        for (int i = 0; i < 4; i++) {
            float4 v = xr[c + i * 32];
            int n0 = (c + i * 32) * 4;
            sm[(n0 + 0) * 20 + j] = v.x;
            sm[(n0 + 1) * 20 + j] = v.y;
            sm[(n0 + 2) * 20 + j] = v.z;
            sm[(n0 + 3) * 20 + j] = v.w;
        }
    }
    __syncthreads();
    int hl = tid & 63, ns = tid >> 6;      // 8 n-segments of 64
    int h  = ht * 64 + hl;
    float acc[16];
#pragma unroll
    for (int j = 0; j < 16; j++) acc[j] = 0.f;
    const float* wp = W + h;
#pragma unroll 4
    for (int n = ns * 64; n < ns * 64 + 64; n++) {
        float w = wp[(size_t)n * NH];                      // coalesced 256B/wave
        const float4* xv = (const float4*)(sm + n * 20);   // wave-uniform -> broadcast
        float4 a0 = xv[0], a1 = xv[1], a2 = xv[2], a3 = xv[3];
        acc[0]  = fmaf(a0.x, w, acc[0]);  acc[1]  = fmaf(a0.y, w, acc[1]);
        acc[2]  = fmaf(a0.z, w, acc[2]);  acc[3]  = fmaf(a0.w, w, acc[3]);
        acc[4]  = fmaf(a1.x, w, acc[4]);  acc[5]  = fmaf(a1.y, w, acc[5]);
        acc[6]  = fmaf(a1.z, w, acc[6]);  acc[7]  = fmaf(a1.w, w, acc[7]);
        acc[8]  = fmaf(a2.x, w, acc[8]);  acc[9]  = fmaf(a2.y, w, acc[9]);
        acc[10] = fmaf(a2.z, w, acc[10]); acc[11] = fmaf(a2.w, w, acc[11]);
        acc[12] = fmaf(a3.x, w, acc[12]); acc[13] = fmaf(a3.y, w, acc[13]);
        acc[14] = fmaf(a3.z, w, acc[14]); acc[15] = fmaf(a3.w, w, acc[15]);
    }
    __syncthreads();                       // xs no longer needed; reuse sm for reduce
    float4* r4 = (float4*)sm;              // red[ns][hl][16] = 32KB
#pragma unroll
    for (int q = 0; q < 4; q++)
        r4[(ns * 1024 + hl * 16) / 4 + q] =
            make_float4(acc[q*4], acc[q*4+1], acc[q*4+2], acc[q*4+3]);
    __syncthreads();
#pragma unroll
    for (int o = tid; o < 1024; o += 512) {
        int hl2 = o >> 4, j2 = o & 15;
        float th = bvec[ht * 64 + hl2];
#pragma unroll
        for (int n2 = 0; n2 < 8; n2++) th += sm[n2 * 1024 + hl2 * 16 + j2];
        float ay = fabsf(th);
        float e  = __expf(-2.0f * ay);
        Tt[(size_t)(ht * 64 + hl2) * NB + bt * 16 + j2] =
            copysignf((1.0f - e) / (1.0f + e), th);
    }
    if (gb == 0 && tid < NB) out[tid] = 0.f;   // zero out before D2's atomics
}

// ===== D2: 256 blocks x 512 thr; block owns k0=2*bid, k0+1; waves split h 8x256.
// tanh(2W) + lncosh(2W) computed on the fly (no t2/LC workspace round-trip).
__global__ __launch_bounds__(512) void k_main(const float* __restrict__ W,
                                              const float* __restrict__ Tt,
                                              const float* __restrict__ x,
                                              const float* __restrict__ a,
                                              const float* __restrict__ Oxy,
                                              float* __restrict__ out) {
    __shared__ float t2s[2 * NH];          // [h][2] interleaved (k0,k1) = 16 KB
    __shared__ float red[16 * NB];         // 4 KB cross-wave reduce
    int tid = threadIdx.x;
    int lane = tid & 63, wv = tid >> 6;    // lane<->b, 8 waves split h
    int k0 = __builtin_amdgcn_readfirstlane(blockIdx.x * 2);
    int hb = wv * 256;                     // this wave's h-range [hb, hb+256)

    // ---- prep: tanh(2W[k][h]) into LDS + per-wave lncosh partial sums ----
    const float2* w0 = (const float2*)(W + (size_t)k0 * NH + hb);
    const float2* w1 = (const float2*)(W + (size_t)(k0 + 1) * NH + hb);
    float lc0 = 0.f, lc1 = 0.f;
#pragma unroll
    for (int i = 0; i < 2; i++) {
        float2 wa = w0[lane + i * 64];     // W[k0][h2], W[k0][h2+1]
        float2 wb = w1[lane + i * 64];     // W[k1][h2], W[k1][h2+1]
        float in[4] = {wa.x, wa.y, wb.x, wb.y};
        float t[4];
#pragma unroll
        for (int j = 0; j < 4; j++) {
            float y  = 2.0f * in[j];
            float ay = fabsf(y);
            float e  = __expf(-2.0f * ay);
            t[j] = copysignf((1.0f - e) / (1.0f + e), y);
            float l = ay + __logf(1.0f + e) - LN2;         // lncosh(y)
            if (j < 2) lc0 += l; else lc1 += l;
        }
        int h2 = hb + (lane + i * 64) * 2;                 // even; float4-aligned
        *(float4*)&t2s[h2 * 2] = make_float4(t[0], t[2], t[1], t[3]);
    }
#pragma unroll
    for (int off = 32; off > 0; off >>= 1) {               // 64-lane butterfly
        lc0 += __shfl_xor(lc0, off);
        lc1 += __shfl_xor(lc1, off);
    }
    float ms0 = -x[(size_t)lane * NN + k0];                // -x[b][k0] (L2 gather)
    float ms1 = -x[(size_t)lane * NN + k0 + 1];
    __syncthreads();                       // cheap insurance; regions are wave-private

    // ---- hot loop: lp starts with this wave's lncosh partial (folds LC in) ----
    float lp0 = lc0, lp1 = lc1;
    for (int h0 = hb; h0 < hb + 256; h0 += 32) {
        float p0 = 1.f, p1 = 1.f;
#pragma unroll
        for (int hh = 0; hh < 32; hh++) {
            int h = h0 + hh;
            float2 t = *(const float2*)&t2s[h * 2];        // uniform ds_read_b64
            float T = Tt[(size_t)h * NB + lane];           // coalesced 256B/wave, L2
            p0 *= fmaf(t.x * T, ms0, 1.0f);                // 1 - s*T*tanh(2W)
            p1 *= fmaf(t.y * T, ms1, 1.0f);
        }
        lp0 += __logf(p0);                 // |ln u| small -> 32-chunk product safe
        lp1 += __logf(p1);
    }
    red[(wv * 2 + 0) * NB + lane] = lp0;
    red[(wv * 2 + 1) * NB + lane] = lp1;
    __syncthreads();
    if (tid < NB) {                        // wave 0 finalizes; lane = b
        float d0 = 2.0f * ms0 * a[k0];     // -2 x a = +2 ms a  (LC already in red)
        float d1 = 2.0f * ms1 * a[k0 + 1];
#pragma unroll
        for (int w2 = 0; w2 < 8; w2++) {
            d0 += red[(w2 * 2 + 0) * NB + tid];
            d1 += red[(w2 * 2 + 1) * NB + tid];
        }
        float c = Oxy[k0] * __expf(d0) + Oxy[k0 + 1] * __expf(d1);
        atomicAdd(&out[tid], c);           // 256 adds per address, device-scope
    }
}

extern "C" void kernel_launch(void* const* d_in, const int* in_sizes, int n_in,
                              void* d_out, int out_size, void* d_ws, size_t ws_size,
                              hipStream_t stream) {
    const float* x    = (const float*)d_in[0];
    const float* W    = (const float*)d_in[1];
    const float* bvec = (const float*)d_in[2];
    const float* a    = (const float*)d_in[3];
    const float* Oxy  = (const float*)d_in[4];
    float* out = (float*)d_out;

    float* Tt = (float*)d_ws + OFF_TT;

    k_theta<<<128, 512, 0, stream>>>(W, x, bvec, Tt, out);
    k_main<<<NN / 2, 512, 0, stream>>>(W, Tt, x, a, Oxy, out);
}